// Round 10
// baseline (141.511 us; speedup 1.0000x reference)
//
#include <hip/hip_runtime.h>
#include <hip/hip_bf16.h>
#include <stdint.h>

#define NFRM 8
#define NPTS 4096
#define NBOX 128
#define NS   32
#define TT   4
#define BB   2
#define FEATC 99
#define OUT1OFF (BB*NBOX*TT*NS*5)   /* 163840 */

/* ---- workspace layout (bytes) ---- */
#define WS_SPK    0u
#define WS_EPK    524288u
#define WS_FEATS  786432u
#define WS_SIDX   13762560u
#define WS_FLAGS  13893632u
#define WS_NCNT   14024704u
#define WS_NLST   14024736u
#define WS_VPK    14155808u
#define WS_VEK    14680096u
#define WS_VORIG  14942240u
#define WS_VCNT   15073312u
#define WS_NB1    15073344u
#define WS_NB2    17170496u
/* end ~21.4 MB */

/* ---------------- K1: validity + packed f32 point arrays ---------------- */
__global__ void k_prep(const float* __restrict__ pts, const float* __restrict__ rois,
                       float4* __restrict__ spk, float2* __restrict__ epk)
{
    int f = blockIdx.x >> 4;
    int n = ((blockIdx.x & 15) << 8) | threadIdx.x;
    __shared__ float bqx[NBOX], bqy[NBOX], brv[NBOX];
    if (threadIdx.x < NBOX){
        const float* bp = rois + (size_t)(f*NBOX + threadIdx.x)*7;
        float bx=bp[0], by=bp[1], dx=bp[3], dy=bp[4];
        float hx=__fmul_rn(dx,0.5f), hy=__fmul_rn(dy,0.5f);
        float hd=sqrtf(__fadd_rn(__fmul_rn(hx,hx),__fmul_rn(hy,hy)));
        brv[threadIdx.x]=ceilf(__fdiv_rn(__fmul_rn(hd,1.1f),0.4f));
        bqx[threadIdx.x]=floorf(__fdiv_rn(__fsub_rn(bx,-75.2f),0.4f));
        bqy[threadIdx.x]=floorf(__fdiv_rn(__fsub_rn(by,-75.2f),0.4f));
    }
    __syncthreads();
    const float* pp = pts + (size_t)(f*NPTS+n)*5;
    float x=pp[0], y=pp[1], z=pp[2], it=pp[3], ts=pp[4];
    float cx=floorf(__fdiv_rn(__fsub_rn(x,-75.2f),0.4f));
    float cy=floorf(__fdiv_rn(__fsub_rn(y,-75.2f),0.4f));
    float v=0.f;
    for (int m=0;m<NBOX;m++)
        if (fabsf(bqx[m]-cx)<brv[m] && fabsf(bqy[m]-cy)<brv[m]){ v=1.f; break; }
    spk[f*NPTS+n]=make_float4(x,y,z,v);
    epk[f*NPTS+n]=make_float2(it,ts);
}

/* ---------------- K1b: order-preserving compaction of valid points ------ */
__global__ __launch_bounds__(1024) void k_valid(
    const float4* __restrict__ spk, const float2* __restrict__ epk,
    float4* __restrict__ vpk, float2* __restrict__ vek,
    int* __restrict__ vorig, int* __restrict__ vcnt)
{
    int f = blockIdx.x;
    int tid = threadIdx.x, wv = tid >> 6, lane = tid & 63;
    __shared__ int wcnt[16];
    __shared__ int sbase;
    if (tid == 0) sbase = 0;
    __syncthreads();
    uint64_t below = (1ull<<lane)-1ull;
    for (int j0=0; j0<NPTS; j0+=1024){
        int j = j0 + tid;
        float4 q = spk[f*NPTS+j];
        float2 e = epk[f*NPTS+j];
        bool pred = q.w > 0.5f;
        uint64_t m = __ballot(pred);
        int lp = __popcll(m & below);
        if (lane == 0) wcnt[wv] = __popcll(m);
        __syncthreads();
        int off = sbase;
        for (int w=0; w<wv; w++) off += wcnt[w];
        if (pred){
            int pos = off + lp;
            float sb = __fadd_rn(__fadd_rn(__fmul_rn(q.x,q.x),__fmul_rn(q.y,q.y)),__fmul_rn(q.z,q.z));
            vpk[f*NPTS+pos] = make_float4(q.x,q.y,q.z,sb);
            vek[f*NPTS+pos] = e;
            vorig[f*NPTS+pos] = j;
        }
        __syncthreads();
        if (tid == 0){ int t=0; for (int w=0;w<16;w++) t+=wcnt[w]; sbase += t; }
        __syncthreads();
    }
    if (tid == 0) vcnt[f] = sbase;
}

/* ---------------- K2: per-box stable top-k -> out0, sidx, flags --------- */
__global__ void k_select(const float4* __restrict__ spk, const float2* __restrict__ epk,
                         const float4* __restrict__ vpk, const int* __restrict__ vorig,
                         const int* __restrict__ vcnt,
                         const float* __restrict__ rois, float* __restrict__ out,
                         int* __restrict__ sidx, int* __restrict__ flags)
{
    int id = blockIdx.x;           /* 0..1023 : (f, m) */
    int f = id >> 7, m = id & 127;
    int lane = threadIdx.x;
    const float* bp = rois + (size_t)(f*NBOX+m)*7;
    float bx=bp[0], by=bp[1], dx=bp[3], dy=bp[4];
    float hx=__fmul_rn(dx,0.5f), hy=__fmul_rn(dy,0.5f);
    float hd=sqrtf(__fadd_rn(__fmul_rn(hx,hx),__fmul_rn(hy,hy)));
    float rr=__fmul_rn(hd,1.1f);

    __shared__ int lt[32], lf[32];
    const float4* fsp = spk + f*NPTS;
    const float4* fvp = vpk + f*NPTS;
    const int*    fvo = vorig + f*NPTS;
    int vc = vcnt[f];
    uint64_t below = (1ull<<lane)-1ull;

    /* phase A: masked candidates from valid list (ascending original idx) */
    int cT=0;
    for (int v0=0; v0<vc; v0+=64){
        int vi = v0 + lane;
        int vic = min(vi, vc-1);
        float4 q = fvp[vic];
        float ddx=__fsub_rn(bx,q.x), ddy=__fsub_rn(by,q.y);
        float dis=sqrtf(__fadd_rn(__fmul_rn(ddx,ddx),__fmul_rn(ddy,ddy)));
        bool pm = (vi < vc) && (dis <= rr);
        uint64_t mT=__ballot(pm);
        if (pm){ int pos=cT+__popcll(mT&below); if (pos<32) lt[pos]=fvo[vic]; }
        cT += __popcll(mT);
        if (cT>=32) break;
    }
    /* phase B: fillers = first 32 original indices failing the mask */
    int cF=0;
    for (int j0=0; j0<NPTS; j0+=64){
        int j=j0+lane;
        float4 q = fsp[j];
        float ddx=__fsub_rn(bx,q.x), ddy=__fsub_rn(by,q.y);
        float dis=sqrtf(__fadd_rn(__fmul_rn(ddx,ddx),__fmul_rn(ddy,ddy)));
        bool fl = !((dis <= rr) && (q.w > 0.5f));
        uint64_t mF=__ballot(fl);
        if (fl){ int pos=cF+__popcll(mF&below); if (pos<32) lf[pos]=j; }
        cF += __popcll(mF);
        if (cF>=32) break;
    }
    __syncthreads();
    cT = min(cT,32);
    if (lane < 32){
        int s = lane;
        bool masked = s < cT;
        int idx = masked ? lt[s] : lf[s-cT];
        float mk = masked ? 1.f : 0.f;
        sidx[(f*NBOX+m)*NS+s]=idx;
        flags[f*NPTS+idx]=1;
        int b = f >> 2, t = f & 3;
        size_t row = (((size_t)(b*NBOX+m))*TT + t)*NS + s;
        float4 q = fsp[idx]; float2 e = epk[f*NPTS+idx];
        float* o0 = out + row*5;
        o0[0]=q.x*mk; o0[1]=q.y*mk; o0[2]=q.z*mk; o0[3]=e.x*mk; o0[4]=e.y*mk;
    }
}

/* ---------------- K3: compact flagged points -> global list ------------- */
__global__ void k_compact(const int* __restrict__ flags, int* __restrict__ gcnt,
                          int* __restrict__ glist)
{
    int f = blockIdx.x;
    for (int i = threadIdx.x; i < NPTS; i += blockDim.x){
        if (flags[f*NPTS+i]){
            int pos = atomicAdd(gcnt, 1);
            glist[pos] = (f<<12) | i;
        }
    }
}

/* ---------------- K4a: neighbor scan -> resolved index lists ------------ */
__global__ __launch_bounds__(256) void k_group(
    const float4* __restrict__ spk,
    const float4* __restrict__ vpk, const int* __restrict__ vcnt,
    const int* __restrict__ gcntp, const int* __restrict__ glist,
    int* __restrict__ nb1, int* __restrict__ nb2)
{
    int gcnt = *gcntp;
    int tid = threadIdx.x;
    int wv = tid >> 6, lane = tid & 63;
    __shared__ int lists[4][48];
    const float RR1 = (float)(0.8*0.8);
    const float RR2 = (float)(1.6*1.6);
    uint64_t below = (1ull<<lane)-1ull;
    int* l1 = lists[wv];
    int* l2 = lists[wv]+16;

    for (int c = blockIdx.x; c*4 < gcnt; c += gridDim.x){
        int li = min(c*4 + wv, gcnt-1);
        int pe = glist[li];
        int f = pe >> 12, n = pe & 4095;
        const float4* fsp = spk + f*NPTS;
        const float4* fvp = vpk + f*NPTS;
        int vc = vcnt[f];
        float4 me = fsp[n];
        float sa = __fadd_rn(__fadd_rn(__fmul_rn(me.x,me.x),__fmul_rn(me.y,me.y)),__fmul_rn(me.z,me.z));
        int cnt1=0, cnt2=0;
        for (int v0=0; v0<vc; v0+=64){
            int vi = v0 + lane;
            int vic = min(vi, vc-1);
            float4 q = fvp[vic];
            float dot = __fadd_rn(__fadd_rn(__fmul_rn(me.x,q.x),__fmul_rn(me.y,q.y)),__fmul_rn(me.z,q.z));
            float d2 = fmaxf(__fsub_rn(__fadd_rn(sa,q.w),__fmul_rn(2.0f,dot)), 0.f);
            bool inb = (vi < vc);
            bool p1 = inb && (d2 < RR1);
            bool p2 = inb && (d2 < RR2);
            uint64_t m1 = __ballot(p1), m2 = __ballot(p2);
            if (p1){ int pos = cnt1 + __popcll(m1 & below); if (pos < 16) l1[pos] = vi; }
            if (p2){ int pos = cnt2 + __popcll(m2 & below); if (pos < 32) l2[pos] = vi; }
            cnt1 += __popcll(m1); cnt2 += __popcll(m2);
            if (cnt1 >= 16 && cnt2 >= 32) break;
        }
        cnt1 = min(cnt1,16); cnt2 = min(cnt2,32);
        if (lane < 16){
            int vi = (cnt1 > 0) ? ((lane < cnt1) ? l1[lane] : l1[0]) : -1;
            nb1[(size_t)li*16 + lane] = vi;
        }
        if (lane < 32){
            int vi = (cnt2 > 0) ? ((lane < cnt2) ? l2[lane] : l2[0]) : -1;
            nb2[(size_t)li*32 + lane] = vi;
        }
    }
}

/* ---------------- K4b: MLP0 (5->16->16->32, 16 nbr), 4 pts/wave --------- */
#define M0TOT 912
__global__ __launch_bounds__(256) void k_mlp0(
    const float4* __restrict__ spk, const float2* __restrict__ epk,
    const float4* __restrict__ vpk, const float2* __restrict__ vek,
    const int* __restrict__ gcntp, const int* __restrict__ glist,
    const int* __restrict__ nb1, float* __restrict__ feats,
    const float* __restrict__ w00,const float* __restrict__ b00,
    const float* __restrict__ w01,const float* __restrict__ b01,
    const float* __restrict__ w02,const float* __restrict__ b02)
{
    int gcnt = *gcntp;
    if ((int)blockIdx.x * 16 >= gcnt) return;

    __shared__ float sw[M0TOT];
    int tid = threadIdx.x;
    {
        const float* srcs[6] = {w00,b00,w01,b01,w02,b02};
        const int offs[6]   = {0,80,96,352,368,880};
        const int cnts[6]   = {80,16,256,16,512,32};
        for (int a=0;a<6;a++)
            for (int i=tid;i<cnts[a];i+=256) sw[offs[a]+i]=srcs[a][i];
    }
    __syncthreads();

    int wv = tid >> 6, lane = tid & 63;
    int g = lane >> 4, k = lane & 15;

    for (int c = blockIdx.x; c*16 < gcnt; c += gridDim.x){
        int li = min(c*16 + wv*4 + g, gcnt-1);
        int pe = glist[li];
        int f = pe >> 12, n = pe & 4095;
        const float4* fsp = spk + f*NPTS;
        const float2* fep = epk + f*NPTS;
        float4 me = fsp[n];
        int vi = nb1[(size_t)li*16 + k];
        float g0,g1,g2,g3,g4;
        {
            float4 q; float2 e;
            if (vi >= 0){ q = vpk[f*NPTS+vi]; e = vek[f*NPTS+vi]; }
            else        { q = fsp[0];         e = fep[0]; }
            g0=__fsub_rn(q.x,me.x); g1=__fsub_rn(q.y,me.y); g2=__fsub_rn(q.z,me.z);
            g3=e.x; g4=e.y;
        }
        float h1[16];
        #pragma unroll
        for (int o=0;o<16;o++){
            float a = sw[80+o];
            a += g0*sw[o*5+0]; a += g1*sw[o*5+1]; a += g2*sw[o*5+2];
            a += g3*sw[o*5+3]; a += g4*sw[o*5+4];
            h1[o] = fmaxf(a,0.f);
        }
        float h2[16];
        #pragma unroll
        for (int o=0;o<16;o++){
            float a = sw[352+o];
            #pragma unroll
            for (int cc=0;cc<16;cc++) a += h1[cc]*sw[96+o*16+cc];
            h2[o] = fmaxf(a,0.f);
        }
        float* fo = feats + (size_t)(f*NPTS+n)*FEATC;
        if (k==0){ fo[0]=me.x; fo[1]=me.y; fo[2]=me.z; }
        #pragma unroll
        for (int o=0;o<32;o++){
            float a = sw[880+o];
            #pragma unroll
            for (int cc=0;cc<16;cc++) a += h2[cc]*sw[368+o*16+cc];
            a = fmaxf(a,0.f);
            a = fmaxf(a, __shfl_xor(a,1));
            a = fmaxf(a, __shfl_xor(a,2));
            a = fmaxf(a, __shfl_xor(a,4));
            a = fmaxf(a, __shfl_xor(a,8));
            if (k==0) fo[3+o]=a;
        }
    }
}

/* ---------------- K4c: MLP1 (5->32->32->64, 32 nbr), 2 pts/wave --------- */
#define M1TOT 3360
__global__ __launch_bounds__(256) void k_mlp1(
    const float4* __restrict__ spk, const float2* __restrict__ epk,
    const float4* __restrict__ vpk, const float2* __restrict__ vek,
    const int* __restrict__ gcntp, const int* __restrict__ glist,
    const int* __restrict__ nb2, float* __restrict__ feats,
    const float* __restrict__ w10,const float* __restrict__ b10,
    const float* __restrict__ w11,const float* __restrict__ b11,
    const float* __restrict__ w12,const float* __restrict__ b12)
{
    int gcnt = *gcntp;
    if ((int)blockIdx.x * 8 >= gcnt) return;

    __shared__ float sw[M1TOT];
    int tid = threadIdx.x;
    {
        const float* srcs[6] = {w10,b10,w11,b11,w12,b12};
        const int offs[6]   = {0,160,192,1216,1248,3296};
        const int cnts[6]   = {160,32,1024,32,2048,64};
        for (int a=0;a<6;a++)
            for (int i=tid;i<cnts[a];i+=256) sw[offs[a]+i]=srcs[a][i];
    }
    __syncthreads();

    int wv = tid >> 6, lane = tid & 63;
    int g = lane >> 5, k = lane & 31;

    for (int c = blockIdx.x; c*8 < gcnt; c += gridDim.x){
        int li = min(c*8 + wv*2 + g, gcnt-1);
        int pe = glist[li];
        int f = pe >> 12, n = pe & 4095;
        const float4* fsp = spk + f*NPTS;
        const float2* fep = epk + f*NPTS;
        float4 me = fsp[n];
        int vi = nb2[(size_t)li*32 + k];
        float g0,g1,g2,g3,g4;
        {
            float4 q; float2 e;
            if (vi >= 0){ q = vpk[f*NPTS+vi]; e = vek[f*NPTS+vi]; }
            else        { q = fsp[0];         e = fep[0]; }
            g0=__fsub_rn(q.x,me.x); g1=__fsub_rn(q.y,me.y); g2=__fsub_rn(q.z,me.z);
            g3=e.x; g4=e.y;
        }
        float h1[32];
        #pragma unroll
        for (int o=0;o<32;o++){
            float a = sw[160+o];
            a += g0*sw[o*5+0]; a += g1*sw[o*5+1]; a += g2*sw[o*5+2];
            a += g3*sw[o*5+3]; a += g4*sw[o*5+4];
            h1[o] = fmaxf(a,0.f);
        }
        float h2[32];
        #pragma unroll
        for (int o=0;o<32;o++){
            float a = sw[1216+o];
            #pragma unroll
            for (int cc=0;cc<32;cc++) a += h1[cc]*sw[192+o*32+cc];
            h2[o] = fmaxf(a,0.f);
        }
        float* fo = feats + (size_t)(f*NPTS+n)*FEATC;
        #pragma unroll
        for (int o=0;o<64;o++){
            float a = sw[3296+o];
            #pragma unroll
            for (int cc=0;cc<32;cc++) a += h2[cc]*sw[1248+o*32+cc];
            a = fmaxf(a,0.f);
            a = fmaxf(a, __shfl_xor(a,1));
            a = fmaxf(a, __shfl_xor(a,2));
            a = fmaxf(a, __shfl_xor(a,4));
            a = fmaxf(a, __shfl_xor(a,8));
            a = fmaxf(a, __shfl_xor(a,16));
            if (k==0) fo[35+o]=a;
        }
    }
}

/* ---------------- K5: gather feats rows -> out1 ------------------------- */
__global__ void k_gather(const float* __restrict__ feats, const int* __restrict__ sidx,
                         float* __restrict__ out)
{
    int id = blockIdx.x;           /* 0..1023 : (f, m) */
    int f = id >> 7, m = id & 127;
    int tid = threadIdx.x;
    int s = tid >> 3, j = tid & 7;
    int idx = sidx[(f*NBOX+m)*NS+s];
    int b = f >> 2, t = f & 3;
    size_t row = (((size_t)(b*NBOX+m))*TT + t)*NS + s;
    const float* fi = feats + (size_t)(f*NPTS+idx)*FEATC;
    float* o1 = out + OUT1OFF + row*FEATC;
    for (int c=j; c<FEATC; c+=8) o1[c]=fi[c];
}

extern "C" void kernel_launch(void* const* d_in, const int* in_sizes, int n_in,
                              void* d_out, int out_size, void* d_ws, size_t ws_size,
                              hipStream_t stream)
{
    const float* pts  = (const float*)d_in[0];
    const float* rois = (const float*)d_in[1];
    const float* w00=(const float*)d_in[2],  *b00=(const float*)d_in[3];
    const float* w01=(const float*)d_in[4],  *b01=(const float*)d_in[5];
    const float* w02=(const float*)d_in[6],  *b02=(const float*)d_in[7];
    const float* w10=(const float*)d_in[8],  *b10=(const float*)d_in[9];
    const float* w11=(const float*)d_in[10], *b11=(const float*)d_in[11];
    const float* w12=(const float*)d_in[12], *b12=(const float*)d_in[13];
    float* out = (float*)d_out;

    char* ws = (char*)d_ws;
    float4* spk   = (float4*)(ws + WS_SPK);
    float2* epk   = (float2*)(ws + WS_EPK);
    float*  feats = (float*) (ws + WS_FEATS);
    int*    sidx  = (int*)   (ws + WS_SIDX);
    int*    flags = (int*)   (ws + WS_FLAGS);
    int*    gcnt  = (int*)   (ws + WS_NCNT);
    int*    glist = (int*)   (ws + WS_NLST);
    float4* vpk   = (float4*)(ws + WS_VPK);
    float2* vek   = (float2*)(ws + WS_VEK);
    int*    vorig = (int*)   (ws + WS_VORIG);
    int*    vcnt  = (int*)   (ws + WS_VCNT);
    int*    nb1   = (int*)   (ws + WS_NB1);
    int*    nb2   = (int*)   (ws + WS_NB2);

    /* zero flags + gcnt each launch (contiguous region) */
    hipMemsetAsync(ws + WS_FLAGS, 0, (WS_NCNT - WS_FLAGS) + 32, stream);

    hipLaunchKernelGGL(k_prep,   dim3(NFRM*16), dim3(256), 0, stream, pts, rois, spk, epk);
    hipLaunchKernelGGL(k_valid,  dim3(NFRM), dim3(1024), 0, stream, spk, epk, vpk, vek, vorig, vcnt);
    hipLaunchKernelGGL(k_select, dim3(NFRM*NBOX), dim3(64), 0, stream,
                       spk, epk, vpk, vorig, vcnt, rois, out, sidx, flags);
    hipLaunchKernelGGL(k_compact, dim3(NFRM), dim3(256), 0, stream, flags, gcnt, glist);
    hipLaunchKernelGGL(k_group,  dim3(2048), dim3(256), 0, stream,
                       spk, vpk, vcnt, gcnt, glist, nb1, nb2);
    hipLaunchKernelGGL(k_mlp0,   dim3(512), dim3(256), 0, stream,
                       spk, epk, vpk, vek, gcnt, glist, nb1, feats,
                       w00,b00,w01,b01,w02,b02);
    hipLaunchKernelGGL(k_mlp1,   dim3(1024), dim3(256), 0, stream,
                       spk, epk, vpk, vek, gcnt, glist, nb2, feats,
                       w10,b10,w11,b11,w12,b12);
    hipLaunchKernelGGL(k_gather, dim3(NFRM*NBOX), dim3(256), 0, stream,
                       feats, sidx, out);
}

// Round 11
// 135.524 us; speedup vs baseline: 1.0442x; 1.0442x over previous
//
#include <hip/hip_runtime.h>
#include <hip/hip_bf16.h>
#include <stdint.h>

#define NFRM 8
#define NPTS 4096
#define NBOX 128
#define NS   32
#define TT   4
#define BB   2
#define FEATC 99
#define OUT1OFF (BB*NBOX*TT*NS*5)   /* 163840 */

/* ---- workspace layout (bytes) ---- */
#define WS_SPK    0u
#define WS_EPK    524288u
#define WS_FEATS  786432u
#define WS_SIDX   13762560u
#define WS_FLAGS  13893632u
#define WS_NCNT   14024704u
#define WS_NLST   14024736u
#define WS_VPK    14155808u
#define WS_VEK    14680096u
#define WS_VORIG  14942240u
#define WS_VCNT   15073312u
/* end ~15.1 MB */

__device__ __forceinline__ float rdl(float x, int l){
    return __int_as_float(__builtin_amdgcn_readlane(__float_as_int(x), l));
}

/* ---------------- K1: validity + packed f32 point arrays ---------------- */
__global__ void k_prep(const float* __restrict__ pts, const float* __restrict__ rois,
                       float4* __restrict__ spk, float2* __restrict__ epk)
{
    int f = blockIdx.x >> 4;
    int n = ((blockIdx.x & 15) << 8) | threadIdx.x;
    __shared__ float bqx[NBOX], bqy[NBOX], brv[NBOX];
    if (threadIdx.x < NBOX){
        const float* bp = rois + (size_t)(f*NBOX + threadIdx.x)*7;
        float bx=bp[0], by=bp[1], dx=bp[3], dy=bp[4];
        float hx=__fmul_rn(dx,0.5f), hy=__fmul_rn(dy,0.5f);
        float hd=sqrtf(__fadd_rn(__fmul_rn(hx,hx),__fmul_rn(hy,hy)));
        brv[threadIdx.x]=ceilf(__fdiv_rn(__fmul_rn(hd,1.1f),0.4f));
        bqx[threadIdx.x]=floorf(__fdiv_rn(__fsub_rn(bx,-75.2f),0.4f));
        bqy[threadIdx.x]=floorf(__fdiv_rn(__fsub_rn(by,-75.2f),0.4f));
    }
    __syncthreads();
    const float* pp = pts + (size_t)(f*NPTS+n)*5;
    float x=pp[0], y=pp[1], z=pp[2], it=pp[3], ts=pp[4];
    float cx=floorf(__fdiv_rn(__fsub_rn(x,-75.2f),0.4f));
    float cy=floorf(__fdiv_rn(__fsub_rn(y,-75.2f),0.4f));
    float v=0.f;
    for (int m=0;m<NBOX;m++)
        if (fabsf(bqx[m]-cx)<brv[m] && fabsf(bqy[m]-cy)<brv[m]){ v=1.f; break; }
    spk[f*NPTS+n]=make_float4(x,y,z,v);
    epk[f*NPTS+n]=make_float2(it,ts);
}

/* ---------------- K1b: order-preserving compaction of valid points ------ */
__global__ __launch_bounds__(1024) void k_valid(
    const float4* __restrict__ spk, const float2* __restrict__ epk,
    float4* __restrict__ vpk, float2* __restrict__ vek,
    int* __restrict__ vorig, int* __restrict__ vcnt)
{
    int f = blockIdx.x;
    int tid = threadIdx.x, wv = tid >> 6, lane = tid & 63;
    __shared__ int wcnt[16];
    __shared__ int sbase;
    if (tid == 0) sbase = 0;
    __syncthreads();
    uint64_t below = (1ull<<lane)-1ull;
    for (int j0=0; j0<NPTS; j0+=1024){
        int j = j0 + tid;
        float4 q = spk[f*NPTS+j];
        float2 e = epk[f*NPTS+j];
        bool pred = q.w > 0.5f;
        uint64_t m = __ballot(pred);
        int lp = __popcll(m & below);
        if (lane == 0) wcnt[wv] = __popcll(m);
        __syncthreads();
        int off = sbase;
        for (int w=0; w<wv; w++) off += wcnt[w];
        if (pred){
            int pos = off + lp;
            float sb = __fadd_rn(__fadd_rn(__fmul_rn(q.x,q.x),__fmul_rn(q.y,q.y)),__fmul_rn(q.z,q.z));
            vpk[f*NPTS+pos] = make_float4(q.x,q.y,q.z,sb);
            vek[f*NPTS+pos] = e;
            vorig[f*NPTS+pos] = j;
        }
        __syncthreads();
        if (tid == 0){ int t=0; for (int w=0;w<16;w++) t+=wcnt[w]; sbase += t; }
        __syncthreads();
    }
    if (tid == 0) vcnt[f] = sbase;
}

/* ---------------- K2: per-box stable top-k -> out0, sidx, flags --------- */
__global__ void k_select(const float4* __restrict__ spk, const float2* __restrict__ epk,
                         const float4* __restrict__ vpk, const int* __restrict__ vorig,
                         const int* __restrict__ vcnt,
                         const float* __restrict__ rois, float* __restrict__ out,
                         int* __restrict__ sidx, int* __restrict__ flags)
{
    int id = blockIdx.x;           /* 0..1023 : (f, m) */
    int f = id >> 7, m = id & 127;
    int lane = threadIdx.x;
    const float* bp = rois + (size_t)(f*NBOX+m)*7;
    float bx=bp[0], by=bp[1], dx=bp[3], dy=bp[4];
    float hx=__fmul_rn(dx,0.5f), hy=__fmul_rn(dy,0.5f);
    float hd=sqrtf(__fadd_rn(__fmul_rn(hx,hx),__fmul_rn(hy,hy)));
    float rr=__fmul_rn(hd,1.1f);

    __shared__ int lt[32], lf[32];
    const float4* fsp = spk + f*NPTS;
    const float4* fvp = vpk + f*NPTS;
    const int*    fvo = vorig + f*NPTS;
    int vc = vcnt[f];
    uint64_t below = (1ull<<lane)-1ull;

    int cT=0;
    for (int v0=0; v0<vc; v0+=64){
        int vi = v0 + lane;
        int vic = min(vi, vc-1);
        float4 q = fvp[vic];
        float ddx=__fsub_rn(bx,q.x), ddy=__fsub_rn(by,q.y);
        float dis=sqrtf(__fadd_rn(__fmul_rn(ddx,ddx),__fmul_rn(ddy,ddy)));
        bool pm = (vi < vc) && (dis <= rr);
        uint64_t mT=__ballot(pm);
        if (pm){ int pos=cT+__popcll(mT&below); if (pos<32) lt[pos]=fvo[vic]; }
        cT += __popcll(mT);
        if (cT>=32) break;
    }
    int cF=0;
    for (int j0=0; j0<NPTS; j0+=64){
        int j=j0+lane;
        float4 q = fsp[j];
        float ddx=__fsub_rn(bx,q.x), ddy=__fsub_rn(by,q.y);
        float dis=sqrtf(__fadd_rn(__fmul_rn(ddx,ddx),__fmul_rn(ddy,ddy)));
        bool fl = !((dis <= rr) && (q.w > 0.5f));
        uint64_t mF=__ballot(fl);
        if (fl){ int pos=cF+__popcll(mF&below); if (pos<32) lf[pos]=j; }
        cF += __popcll(mF);
        if (cF>=32) break;
    }
    __syncthreads();
    cT = min(cT,32);
    if (lane < 32){
        int s = lane;
        bool masked = s < cT;
        int idx = masked ? lt[s] : lf[s-cT];
        float mk = masked ? 1.f : 0.f;
        sidx[(f*NBOX+m)*NS+s]=idx;
        flags[f*NPTS+idx]=1;
        int b = f >> 2, t = f & 3;
        size_t row = (((size_t)(b*NBOX+m))*TT + t)*NS + s;
        float4 q = fsp[idx]; float2 e = epk[f*NPTS+idx];
        float* o0 = out + row*5;
        o0[0]=q.x*mk; o0[1]=q.y*mk; o0[2]=q.z*mk; o0[3]=e.x*mk; o0[4]=e.y*mk;
    }
}

/* ---------------- K3: compact flagged points -> global list ------------- */
__global__ void k_compact(const int* __restrict__ flags, int* __restrict__ gcnt,
                          int* __restrict__ glist)
{
    int f = blockIdx.x;
    for (int i = threadIdx.x; i < NPTS; i += blockDim.x){
        if (flags[f*NPTS+i]){
            int pos = atomicAdd(gcnt, 1);
            glist[pos] = (f<<12) | i;
        }
    }
}

/* ------- K4: scan + channel-major MLPs (weights in VGPRs, no LDS) ------- */
__global__ __launch_bounds__(256) void k_mlp(
    const float4* __restrict__ spk, const float2* __restrict__ epk,
    const float4* __restrict__ vpk, const float2* __restrict__ vek,
    const int* __restrict__ vcnt,
    const int* __restrict__ gcntp, const int* __restrict__ glist,
    float* __restrict__ feats,
    const float* __restrict__ w00,const float* __restrict__ b00,
    const float* __restrict__ w01,const float* __restrict__ b01,
    const float* __restrict__ w02,const float* __restrict__ b02,
    const float* __restrict__ w10,const float* __restrict__ b10,
    const float* __restrict__ w11,const float* __restrict__ b11,
    const float* __restrict__ w12,const float* __restrict__ b12)
{
    int gcnt = *gcntp;
    int tid = threadIdx.x;
    int wv = tid >> 6, lane = tid & 63;
    __shared__ int lists[4][48];
    int* l1 = lists[wv];
    int* l2 = lists[wv]+16;

    /* ---- per-lane weight rows (persistent in VGPRs) ---- */
    float wr00[5], wr01[16], wr02[16], wr10[5], wr11[32], wr12[32];
    float br00=0.f, br01=0.f, br02=0.f, br10=0.f, br11=0.f, br12=0.f;
    #pragma unroll
    for (int i=0;i<5;i++){ wr00[i]=0.f; wr10[i]=0.f; }
    #pragma unroll
    for (int i=0;i<16;i++){ wr01[i]=0.f; wr02[i]=0.f; }
    #pragma unroll
    for (int i=0;i<32;i++){ wr11[i]=0.f; wr12[i]=0.f; }
    if (lane < 16){
        #pragma unroll
        for (int i=0;i<5;i++)  wr00[i]=w00[lane*5+i];
        br00=b00[lane];
        #pragma unroll
        for (int i=0;i<16;i++) wr01[i]=w01[lane*16+i];
        br01=b01[lane];
    }
    if (lane < 32){
        #pragma unroll
        for (int i=0;i<16;i++) wr02[i]=w02[lane*16+i];
        br02=b02[lane];
        #pragma unroll
        for (int i=0;i<5;i++)  wr10[i]=w10[lane*5+i];
        br10=b10[lane];
        #pragma unroll
        for (int i=0;i<32;i++) wr11[i]=w11[lane*32+i];
        br11=b11[lane];
    }
    #pragma unroll
    for (int i=0;i<32;i++) wr12[i]=w12[lane*32+i];
    br12=b12[lane];

    const float RR1 = (float)(0.8*0.8);
    const float RR2 = (float)(1.6*1.6);
    uint64_t below = (1ull<<lane)-1ull;

    for (int li = blockIdx.x*4 + wv; li < gcnt; li += 4096){
        int pe = glist[li];
        int f = pe >> 12, n = pe & 4095;
        const float4* fsp = spk + f*NPTS;
        const float2* fep = epk + f*NPTS;
        const float4* fvp = vpk + f*NPTS;
        const float2* fve = vek + f*NPTS;
        int vc = vcnt[f];
        float4 me = fsp[n];
        float sa = __fadd_rn(__fadd_rn(__fmul_rn(me.x,me.x),__fmul_rn(me.y,me.y)),__fmul_rn(me.z,me.z));

        /* ---- neighbor scan over valid list ---- */
        int cnt1=0, cnt2=0;
        for (int v0=0; v0<vc; v0+=64){
            int vi = v0 + lane;
            int vic = min(vi, vc-1);
            float4 q = fvp[vic];
            float dot = __fadd_rn(__fadd_rn(__fmul_rn(me.x,q.x),__fmul_rn(me.y,q.y)),__fmul_rn(me.z,q.z));
            float d2 = fmaxf(__fsub_rn(__fadd_rn(sa,q.w),__fmul_rn(2.0f,dot)), 0.f);
            bool inb = (vi < vc);
            bool p1 = inb && (d2 < RR1);
            bool p2 = inb && (d2 < RR2);
            uint64_t m1 = __ballot(p1), m2 = __ballot(p2);
            if (p1){ int pos = cnt1 + __popcll(m1 & below); if (pos < 16) l1[pos] = vi; }
            if (p2){ int pos = cnt2 + __popcll(m2 & below); if (pos < 32) l2[pos] = vi; }
            cnt1 += __popcll(m1); cnt2 += __popcll(m2);
            if (cnt1 >= 16 && cnt2 >= 32) break;
        }
        cnt1 = min(cnt1,16); cnt2 = min(cnt2,32);

        float* fo = feats + (size_t)(f*NPTS+n)*FEATC;
        float4 q0 = fsp[0]; float2 e0 = fep[0];

        /* ---- MLP0: 16 nbrs, 5->16->16->32, channel-per-lane ---- */
        {
            float pmax = 0.f;
            /* prefetch nbr 0 */
            int vi_n = (cnt1>0) ? l1[0] : -1;
            float4 q_n; float2 e_n;
            if (vi_n >= 0){ q_n = fvp[vi_n]; e_n = fve[vi_n]; }
            else          { q_n = q0;        e_n = e0; }
            #pragma unroll 1
            for (int k=0;k<16;k++){
                float4 qc = q_n; float2 ec = e_n;
                if (k < 15){
                    int kk = k+1;
                    int vi = (cnt1>0) ? ((kk<cnt1)? l1[kk] : l1[0]) : -1;
                    if (vi >= 0){ q_n = fvp[vi]; e_n = fve[vi]; }
                    else        { q_n = q0;      e_n = e0; }
                }
                float g0=__fsub_rn(qc.x,me.x), g1=__fsub_rn(qc.y,me.y), g2=__fsub_rn(qc.z,me.z);
                float g3=ec.x, g4=ec.y;
                float a1 = br00;
                a1 += g0*wr00[0]; a1 += g1*wr00[1]; a1 += g2*wr00[2];
                a1 += g3*wr00[3]; a1 += g4*wr00[4];
                float h1 = fmaxf(a1,0.f);
                float a2 = br01;
                #pragma unroll
                for (int c=0;c<16;c++) a2 += rdl(h1,c)*wr01[c];
                float h2 = fmaxf(a2,0.f);
                float a3 = br02;
                #pragma unroll
                for (int c=0;c<16;c++) a3 += rdl(h2,c)*wr02[c];
                float h3 = fmaxf(a3,0.f);
                pmax = fmaxf(pmax, h3);
            }
            if (lane < 3){
                float mv = (lane==0)? me.x : ((lane==1)? me.y : me.z);
                fo[lane] = mv;
            }
            if (lane < 32) fo[3+lane] = pmax;
        }

        /* ---- MLP1: 32 nbrs, 5->32->32->64, channel-per-lane ---- */
        {
            float pmax = 0.f;
            int vi_n = (cnt2>0) ? l2[0] : -1;
            float4 q_n; float2 e_n;
            if (vi_n >= 0){ q_n = fvp[vi_n]; e_n = fve[vi_n]; }
            else          { q_n = q0;        e_n = e0; }
            #pragma unroll 1
            for (int k=0;k<32;k++){
                float4 qc = q_n; float2 ec = e_n;
                if (k < 31){
                    int kk = k+1;
                    int vi = (cnt2>0) ? ((kk<cnt2)? l2[kk] : l2[0]) : -1;
                    if (vi >= 0){ q_n = fvp[vi]; e_n = fve[vi]; }
                    else        { q_n = q0;      e_n = e0; }
                }
                float g0=__fsub_rn(qc.x,me.x), g1=__fsub_rn(qc.y,me.y), g2=__fsub_rn(qc.z,me.z);
                float g3=ec.x, g4=ec.y;
                float a1 = br10;
                a1 += g0*wr10[0]; a1 += g1*wr10[1]; a1 += g2*wr10[2];
                a1 += g3*wr10[3]; a1 += g4*wr10[4];
                float h1 = fmaxf(a1,0.f);
                float a2 = br11;
                #pragma unroll
                for (int c=0;c<32;c++) a2 += rdl(h1,c)*wr11[c];
                float h2 = fmaxf(a2,0.f);
                float a3 = br12;
                #pragma unroll
                for (int c=0;c<32;c++) a3 += rdl(h2,c)*wr12[c];
                float h3 = fmaxf(a3,0.f);
                pmax = fmaxf(pmax, h3);
            }
            fo[35+lane] = pmax;
        }
    }
}

/* ---------------- K5: gather feats rows -> out1 ------------------------- */
__global__ void k_gather(const float* __restrict__ feats, const int* __restrict__ sidx,
                         float* __restrict__ out)
{
    int id = blockIdx.x;           /* 0..1023 : (f, m) */
    int f = id >> 7, m = id & 127;
    int tid = threadIdx.x;
    int s = tid >> 3, j = tid & 7;
    int idx = sidx[(f*NBOX+m)*NS+s];
    int b = f >> 2, t = f & 3;
    size_t row = (((size_t)(b*NBOX+m))*TT + t)*NS + s;
    const float* fi = feats + (size_t)(f*NPTS+idx)*FEATC;
    float* o1 = out + OUT1OFF + row*FEATC;
    for (int c=j; c<FEATC; c+=8) o1[c]=fi[c];
}

extern "C" void kernel_launch(void* const* d_in, const int* in_sizes, int n_in,
                              void* d_out, int out_size, void* d_ws, size_t ws_size,
                              hipStream_t stream)
{
    const float* pts  = (const float*)d_in[0];
    const float* rois = (const float*)d_in[1];
    const float* w00=(const float*)d_in[2],  *b00=(const float*)d_in[3];
    const float* w01=(const float*)d_in[4],  *b01=(const float*)d_in[5];
    const float* w02=(const float*)d_in[6],  *b02=(const float*)d_in[7];
    const float* w10=(const float*)d_in[8],  *b10=(const float*)d_in[9];
    const float* w11=(const float*)d_in[10], *b11=(const float*)d_in[11];
    const float* w12=(const float*)d_in[12], *b12=(const float*)d_in[13];
    float* out = (float*)d_out;

    char* ws = (char*)d_ws;
    float4* spk   = (float4*)(ws + WS_SPK);
    float2* epk   = (float2*)(ws + WS_EPK);
    float*  feats = (float*) (ws + WS_FEATS);
    int*    sidx  = (int*)   (ws + WS_SIDX);
    int*    flags = (int*)   (ws + WS_FLAGS);
    int*    gcnt  = (int*)   (ws + WS_NCNT);
    int*    glist = (int*)   (ws + WS_NLST);
    float4* vpk   = (float4*)(ws + WS_VPK);
    float2* vek   = (float2*)(ws + WS_VEK);
    int*    vorig = (int*)   (ws + WS_VORIG);
    int*    vcnt  = (int*)   (ws + WS_VCNT);

    /* zero flags + gcnt each launch (contiguous region) */
    hipMemsetAsync(ws + WS_FLAGS, 0, (WS_NCNT - WS_FLAGS) + 32, stream);

    hipLaunchKernelGGL(k_prep,   dim3(NFRM*16), dim3(256), 0, stream, pts, rois, spk, epk);
    hipLaunchKernelGGL(k_valid,  dim3(NFRM), dim3(1024), 0, stream, spk, epk, vpk, vek, vorig, vcnt);
    hipLaunchKernelGGL(k_select, dim3(NFRM*NBOX), dim3(64), 0, stream,
                       spk, epk, vpk, vorig, vcnt, rois, out, sidx, flags);
    hipLaunchKernelGGL(k_compact, dim3(NFRM), dim3(256), 0, stream, flags, gcnt, glist);
    hipLaunchKernelGGL(k_mlp,    dim3(1024), dim3(256), 0, stream,
                       spk, epk, vpk, vek, vcnt, gcnt, glist, feats,
                       w00,b00,w01,b01,w02,b02,w10,b10,w11,b11,w12,b12);
    hipLaunchKernelGGL(k_gather, dim3(NFRM*NBOX), dim3(256), 0, stream,
                       feats, sidx, out);
}

// Round 12
// 129.256 us; speedup vs baseline: 1.0948x; 1.0485x over previous
//
#include <hip/hip_runtime.h>
#include <hip/hip_bf16.h>
#include <stdint.h>

#define NFRM 8
#define NPTS 4096
#define NBOX 128
#define NS   32
#define TT   4
#define BB   2
#define FEATC 99
#define OUT1OFF (BB*NBOX*TT*NS*5)   /* 163840 */

/* ---- workspace layout (bytes) ---- */
#define WS_SPK    0u
#define WS_EPK    524288u
#define WS_FEATS  786432u
#define WS_SIDX   13762560u
#define WS_FLAGS  13893632u
#define WS_NCNT   14024704u
#define WS_NLST   14024736u
#define WS_VPK    14155808u
#define WS_VEK    14680096u
#define WS_VORIG  14942240u
#define WS_VCNT   15073312u
/* end ~15.1 MB */

__device__ __forceinline__ float rdl(float x, int l){
    return __int_as_float(__builtin_amdgcn_readlane(__float_as_int(x), l));
}

/* ---------------- K1: validity + packed f32 point arrays ---------------- */
__global__ void k_prep(const float* __restrict__ pts, const float* __restrict__ rois,
                       float4* __restrict__ spk, float2* __restrict__ epk)
{
    int f = blockIdx.x >> 4;
    int n = ((blockIdx.x & 15) << 8) | threadIdx.x;
    __shared__ float bqx[NBOX], bqy[NBOX], brv[NBOX];
    if (threadIdx.x < NBOX){
        const float* bp = rois + (size_t)(f*NBOX + threadIdx.x)*7;
        float bx=bp[0], by=bp[1], dx=bp[3], dy=bp[4];
        float hx=__fmul_rn(dx,0.5f), hy=__fmul_rn(dy,0.5f);
        float hd=sqrtf(__fadd_rn(__fmul_rn(hx,hx),__fmul_rn(hy,hy)));
        brv[threadIdx.x]=ceilf(__fdiv_rn(__fmul_rn(hd,1.1f),0.4f));
        bqx[threadIdx.x]=floorf(__fdiv_rn(__fsub_rn(bx,-75.2f),0.4f));
        bqy[threadIdx.x]=floorf(__fdiv_rn(__fsub_rn(by,-75.2f),0.4f));
    }
    __syncthreads();
    const float* pp = pts + (size_t)(f*NPTS+n)*5;
    float x=pp[0], y=pp[1], z=pp[2], it=pp[3], ts=pp[4];
    float cx=floorf(__fdiv_rn(__fsub_rn(x,-75.2f),0.4f));
    float cy=floorf(__fdiv_rn(__fsub_rn(y,-75.2f),0.4f));
    float v=0.f;
    for (int m=0;m<NBOX;m++)
        if (fabsf(bqx[m]-cx)<brv[m] && fabsf(bqy[m]-cy)<brv[m]){ v=1.f; break; }
    spk[f*NPTS+n]=make_float4(x,y,z,v);
    epk[f*NPTS+n]=make_float2(it,ts);
}

/* ---------------- K1b: order-preserving compaction of valid points ------ */
__global__ __launch_bounds__(1024) void k_valid(
    const float4* __restrict__ spk, const float2* __restrict__ epk,
    float4* __restrict__ vpk, float2* __restrict__ vek,
    int* __restrict__ vorig, int* __restrict__ vcnt)
{
    int f = blockIdx.x;
    int tid = threadIdx.x, wv = tid >> 6, lane = tid & 63;
    __shared__ int wcnt[16];
    __shared__ int sbase;
    if (tid == 0) sbase = 0;
    __syncthreads();
    uint64_t below = (1ull<<lane)-1ull;
    for (int j0=0; j0<NPTS; j0+=1024){
        int j = j0 + tid;
        float4 q = spk[f*NPTS+j];
        float2 e = epk[f*NPTS+j];
        bool pred = q.w > 0.5f;
        uint64_t m = __ballot(pred);
        int lp = __popcll(m & below);
        if (lane == 0) wcnt[wv] = __popcll(m);
        __syncthreads();
        int off = sbase;
        for (int w=0; w<wv; w++) off += wcnt[w];
        if (pred){
            int pos = off + lp;
            float sb = __fadd_rn(__fadd_rn(__fmul_rn(q.x,q.x),__fmul_rn(q.y,q.y)),__fmul_rn(q.z,q.z));
            vpk[f*NPTS+pos] = make_float4(q.x,q.y,q.z,sb);
            vek[f*NPTS+pos] = e;
            vorig[f*NPTS+pos] = j;
        }
        __syncthreads();
        if (tid == 0){ int t=0; for (int w=0;w<16;w++) t+=wcnt[w]; sbase += t; }
        __syncthreads();
    }
    if (tid == 0) vcnt[f] = sbase;
}

/* ---------------- K2: per-box stable top-k -> out0, sidx, flags --------- */
__global__ void k_select(const float4* __restrict__ spk, const float2* __restrict__ epk,
                         const float4* __restrict__ vpk, const int* __restrict__ vorig,
                         const int* __restrict__ vcnt,
                         const float* __restrict__ rois, float* __restrict__ out,
                         int* __restrict__ sidx, int* __restrict__ flags)
{
    int id = blockIdx.x;           /* 0..1023 : (f, m) */
    int f = id >> 7, m = id & 127;
    int lane = threadIdx.x;
    const float* bp = rois + (size_t)(f*NBOX+m)*7;
    float bx=bp[0], by=bp[1], dx=bp[3], dy=bp[4];
    float hx=__fmul_rn(dx,0.5f), hy=__fmul_rn(dy,0.5f);
    float hd=sqrtf(__fadd_rn(__fmul_rn(hx,hx),__fmul_rn(hy,hy)));
    float rr=__fmul_rn(hd,1.1f);

    __shared__ int lt[32], lf[32];
    const float4* fsp = spk + f*NPTS;
    const float4* fvp = vpk + f*NPTS;
    const int*    fvo = vorig + f*NPTS;
    int vc = vcnt[f];
    uint64_t below = (1ull<<lane)-1ull;

    int cT=0;
    for (int v0=0; v0<vc; v0+=64){
        int vi = v0 + lane;
        int vic = min(vi, vc-1);
        float4 q = fvp[vic];
        float ddx=__fsub_rn(bx,q.x), ddy=__fsub_rn(by,q.y);
        float dis=sqrtf(__fadd_rn(__fmul_rn(ddx,ddx),__fmul_rn(ddy,ddy)));
        bool pm = (vi < vc) && (dis <= rr);
        uint64_t mT=__ballot(pm);
        if (pm){ int pos=cT+__popcll(mT&below); if (pos<32) lt[pos]=fvo[vic]; }
        cT += __popcll(mT);
        if (cT>=32) break;
    }
    int cF=0;
    for (int j0=0; j0<NPTS; j0+=64){
        int j=j0+lane;
        float4 q = fsp[j];
        float ddx=__fsub_rn(bx,q.x), ddy=__fsub_rn(by,q.y);
        float dis=sqrtf(__fadd_rn(__fmul_rn(ddx,ddx),__fmul_rn(ddy,ddy)));
        bool fl = !((dis <= rr) && (q.w > 0.5f));
        uint64_t mF=__ballot(fl);
        if (fl){ int pos=cF+__popcll(mF&below); if (pos<32) lf[pos]=j; }
        cF += __popcll(mF);
        if (cF>=32) break;
    }
    __syncthreads();
    cT = min(cT,32);
    if (lane < 32){
        int s = lane;
        bool masked = s < cT;
        int idx = masked ? lt[s] : lf[s-cT];
        float mk = masked ? 1.f : 0.f;
        sidx[(f*NBOX+m)*NS+s]=idx;
        flags[f*NPTS+idx]=1;
        int b = f >> 2, t = f & 3;
        size_t row = (((size_t)(b*NBOX+m))*TT + t)*NS + s;
        float4 q = fsp[idx]; float2 e = epk[f*NPTS+idx];
        float* o0 = out + row*5;
        o0[0]=q.x*mk; o0[1]=q.y*mk; o0[2]=q.z*mk; o0[3]=e.x*mk; o0[4]=e.y*mk;
    }
}

/* ---------------- K3: compact flagged points -> global list ------------- */
__global__ void k_compact(const int* __restrict__ flags, int* __restrict__ gcnt,
                          int* __restrict__ glist)
{
    int f = blockIdx.x;
    for (int i = threadIdx.x; i < NPTS; i += blockDim.x){
        if (flags[f*NPTS+i]){
            int pos = atomicAdd(gcnt, 1);
            glist[pos] = (f<<12) | i;
        }
    }
}

/* ------- K4: scan + channel-major MLPs (weights in VGPRs), ILP-4 -------- */
__global__ __launch_bounds__(256) void k_mlp(
    const float4* __restrict__ spk, const float2* __restrict__ epk,
    const float4* __restrict__ vpk, const float2* __restrict__ vek,
    const int* __restrict__ vcnt,
    const int* __restrict__ gcntp, const int* __restrict__ glist,
    float* __restrict__ feats,
    const float* __restrict__ w00,const float* __restrict__ b00,
    const float* __restrict__ w01,const float* __restrict__ b01,
    const float* __restrict__ w02,const float* __restrict__ b02,
    const float* __restrict__ w10,const float* __restrict__ b10,
    const float* __restrict__ w11,const float* __restrict__ b11,
    const float* __restrict__ w12,const float* __restrict__ b12)
{
    int gcnt = *gcntp;
    if ((int)blockIdx.x * 4 >= gcnt) return;
    int tid = threadIdx.x;
    int wv = tid >> 6, lane = tid & 63;
    __shared__ int lists[4][48];
    int* l1 = lists[wv];
    int* l2 = lists[wv]+16;

    /* ---- per-lane weight rows (persistent in VGPRs) ---- */
    float wr00[5], wr01[16], wr02[16], wr10[5], wr11[32], wr12[32];
    float br00=0.f, br01=0.f, br02=0.f, br10=0.f, br11=0.f, br12=0.f;
    #pragma unroll
    for (int i=0;i<5;i++){ wr00[i]=0.f; wr10[i]=0.f; }
    #pragma unroll
    for (int i=0;i<16;i++){ wr01[i]=0.f; wr02[i]=0.f; }
    #pragma unroll
    for (int i=0;i<32;i++){ wr11[i]=0.f; wr12[i]=0.f; }
    if (lane < 16){
        #pragma unroll
        for (int i=0;i<5;i++)  wr00[i]=w00[lane*5+i];
        br00=b00[lane];
        #pragma unroll
        for (int i=0;i<16;i++) wr01[i]=w01[lane*16+i];
        br01=b01[lane];
    }
    if (lane < 32){
        #pragma unroll
        for (int i=0;i<16;i++) wr02[i]=w02[lane*16+i];
        br02=b02[lane];
        #pragma unroll
        for (int i=0;i<5;i++)  wr10[i]=w10[lane*5+i];
        br10=b10[lane];
        #pragma unroll
        for (int i=0;i<32;i++) wr11[i]=w11[lane*32+i];
        br11=b11[lane];
    }
    #pragma unroll
    for (int i=0;i<32;i++) wr12[i]=w12[lane*32+i];
    br12=b12[lane];

    const float RR1 = (float)(0.8*0.8);
    const float RR2 = (float)(1.6*1.6);
    uint64_t below = (1ull<<lane)-1ull;

    for (int li = blockIdx.x*4 + wv; li < gcnt; li += 8192){
        int pe = glist[li];
        int f = pe >> 12, n = pe & 4095;
        const float4* fsp = spk + f*NPTS;
        const float2* fep = epk + f*NPTS;
        const float4* fvp = vpk + f*NPTS;
        const float2* fve = vek + f*NPTS;
        int vc = vcnt[f];
        float4 me = fsp[n];
        float sa = __fadd_rn(__fadd_rn(__fmul_rn(me.x,me.x),__fmul_rn(me.y,me.y)),__fmul_rn(me.z,me.z));

        /* ---- neighbor scan over valid list ---- */
        int cnt1=0, cnt2=0;
        for (int v0=0; v0<vc; v0+=64){
            int vi = v0 + lane;
            int vic = min(vi, vc-1);
            float4 q = fvp[vic];
            float dot = __fadd_rn(__fadd_rn(__fmul_rn(me.x,q.x),__fmul_rn(me.y,q.y)),__fmul_rn(me.z,q.z));
            float d2 = fmaxf(__fsub_rn(__fadd_rn(sa,q.w),__fmul_rn(2.0f,dot)), 0.f);
            bool inb = (vi < vc);
            bool p1 = inb && (d2 < RR1);
            bool p2 = inb && (d2 < RR2);
            uint64_t m1 = __ballot(p1), m2 = __ballot(p2);
            if (p1){ int pos = cnt1 + __popcll(m1 & below); if (pos < 16) l1[pos] = vi; }
            if (p2){ int pos = cnt2 + __popcll(m2 & below); if (pos < 32) l2[pos] = vi; }
            cnt1 += __popcll(m1); cnt2 += __popcll(m2);
            if (cnt1 >= 16 && cnt2 >= 32) break;
        }
        cnt1 = min(cnt1,16); cnt2 = min(cnt2,32);

        float* fo = feats + (size_t)(f*NPTS+n)*FEATC;
        float4 q0 = fsp[0]; float2 e0 = fep[0];

        /* ---- MLP0: 16 nbrs, 5->16->16->32, batches of 4 (ILP) ---- */
        {
            float pmax = 0.f;
            #pragma unroll 1
            for (int kb=0; kb<16; kb+=4){
                float4 qb[4]; float2 eb[4];
                #pragma unroll
                for (int j=0;j<4;j++){
                    int kk = kb+j;
                    int vi = (cnt1>0) ? ((kk<cnt1)? l1[kk] : l1[0]) : -1;
                    if (vi >= 0){ qb[j]=fvp[vi]; eb[j]=fve[vi]; }
                    else        { qb[j]=q0;      eb[j]=e0; }
                }
                float h1[4];
                #pragma unroll
                for (int j=0;j<4;j++){
                    float a1 = br00;
                    a1 += __fsub_rn(qb[j].x,me.x)*wr00[0];
                    a1 += __fsub_rn(qb[j].y,me.y)*wr00[1];
                    a1 += __fsub_rn(qb[j].z,me.z)*wr00[2];
                    a1 += eb[j].x*wr00[3];
                    a1 += eb[j].y*wr00[4];
                    h1[j] = fmaxf(a1,0.f);
                }
                float a2[4] = {br01,br01,br01,br01};
                #pragma unroll
                for (int c=0;c<16;c++){
                    #pragma unroll
                    for (int j=0;j<4;j++) a2[j] += rdl(h1[j],c)*wr01[c];
                }
                float h2[4];
                #pragma unroll
                for (int j=0;j<4;j++) h2[j] = fmaxf(a2[j],0.f);
                float a3[4] = {br02,br02,br02,br02};
                #pragma unroll
                for (int c=0;c<16;c++){
                    #pragma unroll
                    for (int j=0;j<4;j++) a3[j] += rdl(h2[j],c)*wr02[c];
                }
                #pragma unroll
                for (int j=0;j<4;j++) pmax = fmaxf(pmax, fmaxf(a3[j],0.f));
            }
            if (lane < 3){
                float mv = (lane==0)? me.x : ((lane==1)? me.y : me.z);
                fo[lane] = mv;
            }
            if (lane < 32) fo[3+lane] = pmax;
        }

        /* ---- MLP1: 32 nbrs, 5->32->32->64, batches of 4 (ILP) ---- */
        {
            float pmax = 0.f;
            #pragma unroll 1
            for (int kb=0; kb<32; kb+=4){
                float4 qb[4]; float2 eb[4];
                #pragma unroll
                for (int j=0;j<4;j++){
                    int kk = kb+j;
                    int vi = (cnt2>0) ? ((kk<cnt2)? l2[kk] : l2[0]) : -1;
                    if (vi >= 0){ qb[j]=fvp[vi]; eb[j]=fve[vi]; }
                    else        { qb[j]=q0;      eb[j]=e0; }
                }
                float h1[4];
                #pragma unroll
                for (int j=0;j<4;j++){
                    float a1 = br10;
                    a1 += __fsub_rn(qb[j].x,me.x)*wr10[0];
                    a1 += __fsub_rn(qb[j].y,me.y)*wr10[1];
                    a1 += __fsub_rn(qb[j].z,me.z)*wr10[2];
                    a1 += eb[j].x*wr10[3];
                    a1 += eb[j].y*wr10[4];
                    h1[j] = fmaxf(a1,0.f);
                }
                float a2[4] = {br11,br11,br11,br11};
                #pragma unroll
                for (int c=0;c<32;c++){
                    #pragma unroll
                    for (int j=0;j<4;j++) a2[j] += rdl(h1[j],c)*wr11[c];
                }
                float h2[4];
                #pragma unroll
                for (int j=0;j<4;j++) h2[j] = fmaxf(a2[j],0.f);
                float a3[4] = {br12,br12,br12,br12};
                #pragma unroll
                for (int c=0;c<32;c++){
                    #pragma unroll
                    for (int j=0;j<4;j++) a3[j] += rdl(h2[j],c)*wr12[c];
                }
                #pragma unroll
                for (int j=0;j<4;j++) pmax = fmaxf(pmax, fmaxf(a3[j],0.f));
            }
            fo[35+lane] = pmax;
        }
    }
}

/* ---------------- K5: gather feats rows -> out1 ------------------------- */
__global__ void k_gather(const float* __restrict__ feats, const int* __restrict__ sidx,
                         float* __restrict__ out)
{
    int id = blockIdx.x;           /* 0..1023 : (f, m) */
    int f = id >> 7, m = id & 127;
    int tid = threadIdx.x;
    int s = tid >> 3, j = tid & 7;
    int idx = sidx[(f*NBOX+m)*NS+s];
    int b = f >> 2, t = f & 3;
    size_t row = (((size_t)(b*NBOX+m))*TT + t)*NS + s;
    const float* fi = feats + (size_t)(f*NPTS+idx)*FEATC;
    float* o1 = out + OUT1OFF + row*FEATC;
    for (int c=j; c<FEATC; c+=8) o1[c]=fi[c];
}

extern "C" void kernel_launch(void* const* d_in, const int* in_sizes, int n_in,
                              void* d_out, int out_size, void* d_ws, size_t ws_size,
                              hipStream_t stream)
{
    const float* pts  = (const float*)d_in[0];
    const float* rois = (const float*)d_in[1];
    const float* w00=(const float*)d_in[2],  *b00=(const float*)d_in[3];
    const float* w01=(const float*)d_in[4],  *b01=(const float*)d_in[5];
    const float* w02=(const float*)d_in[6],  *b02=(const float*)d_in[7];
    const float* w10=(const float*)d_in[8],  *b10=(const float*)d_in[9];
    const float* w11=(const float*)d_in[10], *b11=(const float*)d_in[11];
    const float* w12=(const float*)d_in[12], *b12=(const float*)d_in[13];
    float* out = (float*)d_out;

    char* ws = (char*)d_ws;
    float4* spk   = (float4*)(ws + WS_SPK);
    float2* epk   = (float2*)(ws + WS_EPK);
    float*  feats = (float*) (ws + WS_FEATS);
    int*    sidx  = (int*)   (ws + WS_SIDX);
    int*    flags = (int*)   (ws + WS_FLAGS);
    int*    gcnt  = (int*)   (ws + WS_NCNT);
    int*    glist = (int*)   (ws + WS_NLST);
    float4* vpk   = (float4*)(ws + WS_VPK);
    float2* vek   = (float2*)(ws + WS_VEK);
    int*    vorig = (int*)   (ws + WS_VORIG);
    int*    vcnt  = (int*)   (ws + WS_VCNT);

    /* zero flags + gcnt each launch (contiguous region) */
    hipMemsetAsync(ws + WS_FLAGS, 0, (WS_NCNT - WS_FLAGS) + 32, stream);

    hipLaunchKernelGGL(k_prep,   dim3(NFRM*16), dim3(256), 0, stream, pts, rois, spk, epk);
    hipLaunchKernelGGL(k_valid,  dim3(NFRM), dim3(1024), 0, stream, spk, epk, vpk, vek, vorig, vcnt);
    hipLaunchKernelGGL(k_select, dim3(NFRM*NBOX), dim3(64), 0, stream,
                       spk, epk, vpk, vorig, vcnt, rois, out, sidx, flags);
    hipLaunchKernelGGL(k_compact, dim3(NFRM), dim3(256), 0, stream, flags, gcnt, glist);
    hipLaunchKernelGGL(k_mlp,    dim3(2048), dim3(256), 0, stream,
                       spk, epk, vpk, vek, vcnt, gcnt, glist, feats,
                       w00,b00,w01,b01,w02,b02,w10,b10,w11,b11,w12,b12);
    hipLaunchKernelGGL(k_gather, dim3(NFRM*NBOX), dim3(256), 0, stream,
                       feats, sidx, out);
}